// Round 4
// baseline (197.974 us; speedup 1.0000x reference)
//
#include <hip/hip_runtime.h>
#include <hip/hip_bf16.h>

typedef __hip_bfloat16 bf16;

constexpr int CB = 8;     // batch
constexpr int CT = 512;   // T
constexpr int CN = 64;    // N
constexpr int CD = 128;   // D
constexpr int CP = 96;    // PRED
constexpr int CH = 8;     // HEADS
constexpr int CDH = 16;   // head dim
constexpr int CHID = 256; // HID
constexpr int CM = 32;    // CEM freq tokens
constexpr int CG = 64;    // TEM freq tokens
constexpr float TWO_PI = 6.28318530717958647692f;

__device__ __forceinline__ float LD(const void* p, size_t i, bool f) {
  return f ? ((const float*)p)[i] : __bfloat162float(((const bf16*)p)[i]);
}
template <bool F32>
__device__ __forceinline__ float LDT(const void* p, size_t i) {
  return F32 ? ((const float*)p)[i] : __bfloat162float(((const bf16*)p)[i]);
}
__device__ __forceinline__ float b2f(short s) {
  return __uint_as_float(((unsigned int)(unsigned short)s) << 16);
}
__device__ __forceinline__ float rdlane(float v, int l) {
  return __int_as_float(__builtin_amdgcn_readlane(__float_as_int(v), l));
}

__device__ __forceinline__ bool detect_f32(const void* x) {
  const unsigned int* xw = (const unsigned int*)x;
  unsigned int w = xw[threadIdx.x & 63];
  unsigned int e = (w >> 7) & 0xFF;
  unsigned long long m = __ballot(e >= 0x90 || e <= 0x60);
  return __popcll(m) > 3;
}

struct MArgs {
  const void *x, *dec_w, *dec_b, *out_w, *emb, *cWq, *cWk, *cWv, *cWo;
  const void *tWq, *tWk, *tWv, *tWo, *drw, *drb, *out_b, *wfuse;
  const void *w1, *b1, *w2, *b2, *w3, *b3;
  float *trendo, *Pbuf, *ewq, *ewk, *ewv, *wod, *owr, *owi;
  void* out;
};

// ================= kS2 v4: k2 GEMMs with float4/short4 weight loads =================
// GEMM1/2: thread = (tt = tid>>6 t-quarter, cq = tid&63 4-col group); 4x fewer VMEM
// instrs; partial sums reduced through LDS (part buffer, sm+2560..4608).
template <bool F32>
__device__ void k2_body(float* sm, const MArgs& a) {
  float* xbuf = sm;          // [512][3] padded (dead after decomp)
  float* rows = sm;          // [2][512] aliases xbuf (written after sync)
  float* h1 = sm + 1536;     // [2][256]
  float* h2 = sm + 2048;     // [2][256]
  float* part = sm + 2560;   // [4 tt][2 rows][256 cols] = 2048
  int r0 = blockIdx.x * 2;
  int b = r0 >> 6, n0 = r0 & 63;
  int tid = threadIdx.x;
  size_t xb = (size_t)b * CT * CN + n0;
  for (int i = tid; i < CT * 2; i += 256) {
    int t = i >> 1, q = i & 1;
    xbuf[t * 3 + q] = LDT<F32>(a.x, xb + (size_t)t * CN + q);
  }
  __syncthreads();
  float trv[4];
  int q = tid & 1, tl = tid >> 1, t0 = tl * 4;
  {
    float w0 = LDT<F32>(a.dec_w, 0), w1 = LDT<F32>(a.dec_w, 1);
    float c0 = LDT<F32>(a.dec_b, 0), c1 = LDT<F32>(a.dec_b, 1);
    float s17 = 0.f, s49 = 0.f;
    #pragma unroll
    for (int o = -8; o <= 8; ++o) {
      int u = t0 + o; u = u < 0 ? 0 : (u > CT - 1 ? CT - 1 : u);
      s17 += xbuf[u * 3 + q];
    }
    #pragma unroll
    for (int o = -24; o <= 24; ++o) {
      int u = t0 + o; u = u < 0 ? 0 : (u > CT - 1 ? CT - 1 : u);
      s49 += xbuf[u * 3 + q];
    }
    #pragma unroll
    for (int k = 0; k < 4; ++k) {
      int t = t0 + k;
      if (k > 0) {
        int up8 = t + 8 > CT - 1 ? CT - 1 : t + 8;
        int dn9 = t - 9 < 0 ? 0 : t - 9;
        int up24 = t + 24 > CT - 1 ? CT - 1 : t + 24;
        int dn25 = t - 25 < 0 ? 0 : t - 25;
        s17 += xbuf[up8 * 3 + q] - xbuf[dn9 * 3 + q];
        s49 += xbuf[up24 * 3 + q] - xbuf[dn25 * 3 + q];
      }
      float m0 = s17 * (1.f / 17.f), m1 = s49 * (1.f / 49.f);
      float xv = xbuf[t * 3 + q];
      float l0 = xv * w0 + c0, l1 = xv * w1 + c1;
      float mx = fmaxf(l0, l1);
      float e0 = __expf(l0 - mx), e1 = __expf(l1 - mx);
      trv[k] = (e0 * m0 + e1 * m1) / (e0 + e1);
    }
  }
  __syncthreads();  // all xbuf reads done before aliasing writes
  #pragma unroll
  for (int k = 0; k < 4; ++k) rows[q * CT + t0 + k] = trv[k];
  __syncthreads();
  int tt = tid >> 6, cq = tid & 63;
  // ---- GEMM1: [2 rows] x [T=512 -> 256], vectorized ----
  {
    float ac0 = 0, ac1 = 0, ac2 = 0, ac3 = 0, ac4 = 0, ac5 = 0, ac6 = 0, ac7 = 0;
    int tg = tt * 128;
    if (F32) {
      const float4* w4 = (const float4*)a.w1;
      #pragma unroll 8
      for (int t = tg; t < tg + 128; ++t) {
        float4 wv = w4[t * 64 + cq];
        float rA = rows[t], rB = rows[CT + t];
        ac0 = fmaf(rA, wv.x, ac0); ac1 = fmaf(rA, wv.y, ac1);
        ac2 = fmaf(rA, wv.z, ac2); ac3 = fmaf(rA, wv.w, ac3);
        ac4 = fmaf(rB, wv.x, ac4); ac5 = fmaf(rB, wv.y, ac5);
        ac6 = fmaf(rB, wv.z, ac6); ac7 = fmaf(rB, wv.w, ac7);
      }
    } else {
      const short4* w4 = (const short4*)a.w1;
      #pragma unroll 8
      for (int t = tg; t < tg + 128; ++t) {
        short4 sv = w4[t * 64 + cq];
        float wx = b2f(sv.x), wy = b2f(sv.y), wz = b2f(sv.z), ww = b2f(sv.w);
        float rA = rows[t], rB = rows[CT + t];
        ac0 = fmaf(rA, wx, ac0); ac1 = fmaf(rA, wy, ac1);
        ac2 = fmaf(rA, wz, ac2); ac3 = fmaf(rA, ww, ac3);
        ac4 = fmaf(rB, wx, ac4); ac5 = fmaf(rB, wy, ac5);
        ac6 = fmaf(rB, wz, ac6); ac7 = fmaf(rB, ww, ac7);
      }
    }
    float4* pp = (float4*)(part + tt * 512 + cq * 4);
    pp[0] = make_float4(ac0, ac1, ac2, ac3);
    pp[64] = make_float4(ac4, ac5, ac6, ac7);
  }
  __syncthreads();
  {
    int c = tid;
    float bias = LDT<F32>(a.b1, c);
    float s0 = part[c] + part[512 + c] + part[1024 + c] + part[1536 + c];
    float s1 = part[256 + c] + part[768 + c] + part[1280 + c] + part[1792 + c];
    h1[c] = fmaxf(s0 + bias, 0.f);
    h1[CHID + c] = fmaxf(s1 + bias, 0.f);
  }
  __syncthreads();
  // ---- GEMM2: [2 rows] x [256 -> 256], vectorized ----
  {
    float ac0 = 0, ac1 = 0, ac2 = 0, ac3 = 0, ac4 = 0, ac5 = 0, ac6 = 0, ac7 = 0;
    int ig = tt * 64;
    if (F32) {
      const float4* w4 = (const float4*)a.w2;
      #pragma unroll 8
      for (int i = ig; i < ig + 64; ++i) {
        float4 wv = w4[i * 64 + cq];
        float rA = h1[i], rB = h1[CHID + i];
        ac0 = fmaf(rA, wv.x, ac0); ac1 = fmaf(rA, wv.y, ac1);
        ac2 = fmaf(rA, wv.z, ac2); ac3 = fmaf(rA, wv.w, ac3);
        ac4 = fmaf(rB, wv.x, ac4); ac5 = fmaf(rB, wv.y, ac5);
        ac6 = fmaf(rB, wv.z, ac6); ac7 = fmaf(rB, wv.w, ac7);
      }
    } else {
      const short4* w4 = (const short4*)a.w2;
      #pragma unroll 8
      for (int i = ig; i < ig + 64; ++i) {
        short4 sv = w4[i * 64 + cq];
        float wx = b2f(sv.x), wy = b2f(sv.y), wz = b2f(sv.z), ww = b2f(sv.w);
        float rA = h1[i], rB = h1[CHID + i];
        ac0 = fmaf(rA, wx, ac0); ac1 = fmaf(rA, wy, ac1);
        ac2 = fmaf(rA, wz, ac2); ac3 = fmaf(rA, ww, ac3);
        ac4 = fmaf(rB, wx, ac4); ac5 = fmaf(rB, wy, ac5);
        ac6 = fmaf(rB, wz, ac6); ac7 = fmaf(rB, ww, ac7);
      }
    }
    float4* pp = (float4*)(part + tt * 512 + cq * 4);
    pp[0] = make_float4(ac0, ac1, ac2, ac3);
    pp[64] = make_float4(ac4, ac5, ac6, ac7);
  }
  __syncthreads();
  {
    int c = tid;
    float bias = LDT<F32>(a.b2, c);
    float s0 = part[c] + part[512 + c] + part[1024 + c] + part[1536 + c];
    float s1 = part[256 + c] + part[768 + c] + part[1280 + c] + part[1792 + c];
    h2[c] = fmaxf(s0 + bias, 0.f);
    h2[CHID + c] = fmaxf(s1 + bias, 0.f);
  }
  __syncthreads();
  if (tid < 2 * CP) {
    int p = tid < CP ? tid : tid - CP;
    int qh = tid < CP ? 0 : 1;
    float bias = LDT<F32>(a.b3, p);
    float a0 = 0.f;
    #pragma unroll 16
    for (int i = 0; i < CHID; ++i)
      a0 = fmaf(h2[qh * CHID + i], LDT<F32>(a.w3, i * CP + p), a0);
    a.trendo[((size_t)(b * CN + n0 + qh)) * CP + p] = a0 + bias;
  }
}

__global__ __launch_bounds__(256, 4) void kS2(MArgs a) {
  __shared__ __align__(16) float sm[4608];
  bool f32 = detect_f32(a.x);
  int blk = blockIdx.x, tid = threadIdx.x;
  if (blk < 256) {
    if (f32) k2_body<true>(sm, a);
    else     k2_body<false>(sm, a);
  } else if (blk < 1280) {
    // ---- k3: inline res + CEM collapsed attention, 4 t per block (1/wave) ----
    float* xl = sm;                    // [52][64] = 3328 (dead after residual)
    float2* SL = (float2*)sm;          // [4][256] float2, aliases xl (written late)
    float* chp = sm + 3328;            // [512] early scratch
    float* rowl = sm + 3328;           // [4][64] aliases chp (written after chp dead)
    float* Rr = sm + 3584;             // [4][32]
    float* Ri = sm + 3712;
    float* aR = sm + 3840;
    float* prod = sm + 3968;           // [128]
    float* chl = sm + 4096;            // [8]
    float* eml = sm + 4104;            // [128]
    int bk = blk - 256;
    int b = bk >> 7, tbase = (bk & 127) * 4;
    int w = tid >> 6, lane = tid & 63;
    size_t xb = (size_t)b * CT * CN;
    for (int i = tid; i < 52 * 64; i += 256) {
      int r = i >> 6, n = i & 63;
      int u = tbase - 24 + r; u = u < 0 ? 0 : (u > CT - 1 ? CT - 1 : u);
      xl[i] = LD(a.x, xb + (size_t)u * CN + n, f32);
    }
    if (tid < 128) eml[tid] = LD(a.emb, tid, f32);
    __syncthreads();
    // ch: row-coalesced partial dots; wave w -> (matrix = w>>1, d-half = w&1)
    {
      const void* Wm = (w < 2) ? a.cWq : a.cWk;
      int d0 = (w & 1) * 64;
      float p0 = 0.f, p1 = 0.f;
      #pragma unroll 16
      for (int d = d0; d < d0 + 64; ++d) {
        float em = eml[d];
        p0 = fmaf(em, LD(Wm, (size_t)d * CD + lane, f32), p0);
        p1 = fmaf(em, LD(Wm, (size_t)d * CD + 64 + lane, f32), p1);
      }
      chp[w * 128 + lane] = p0;
      chp[w * 128 + 64 + lane] = p1;
    }
    __syncthreads();
    if (tid < 128) {
      float pq = chp[tid] + chp[128 + tid];
      float pk = chp[256 + tid] + chp[384 + tid];
      prod[tid] = pq * pk;
    }
    __syncthreads();
    if (tid < CH) {
      float s = 0;
      #pragma unroll
      for (int j = 0; j < 16; ++j) s += prod[tid * 16 + j];
      chl[tid] = fabsf(s);
    }
    // inline residual: s17 as subset of s49 (49 reads, partial accumulators)
    {
      int Lt = 24 + w;
      float w0 = LD(a.dec_w, 0, f32), w1 = LD(a.dec_w, 1, f32);
      float c0 = LD(a.dec_b, 0, f32), c1 = LD(a.dec_b, 1, f32);
      const float* xc = xl + Lt * 64 + lane;
      float pa = 0.f, pb = 0.f;
      #pragma unroll
      for (int o = -8; o <= 8; o += 2) pa += xc[o * 64];
      #pragma unroll
      for (int o = -7; o <= 7; o += 2) pb += xc[o * 64];
      float s17 = pa + pb;
      float qa = 0.f, qb = 0.f;
      #pragma unroll
      for (int o = 9; o <= 23; o += 2) qa += xc[o * 64] + xc[-o * 64];
      #pragma unroll
      for (int o = 10; o <= 24; o += 2) qb += xc[o * 64] + xc[-o * 64];
      float s49 = s17 + qa + qb;
      float m0 = s17 * (1.f / 17.f), m1 = s49 * (1.f / 49.f);
      float xv = xc[0];
      float l0 = xv * w0 + c0, l1 = xv * w1 + c1;
      float mx = fmaxf(l0, l1);
      float e0 = __expf(l0 - mx), e1 = __expf(l1 - mx);
      float tr = (e0 * m0 + e1 * m1) / (e0 + e1);
      rowl[w * 64 + lane] = xv - tr;
    }
    __syncthreads();
    // R-DFT over n, full wave: lane = (m, half); half sums 32 n-terms.
    float am, amax;
    {
      int m = lane & 31, half = lane >> 5;
      float cf, sf;
      sincosf((float)m * (TWO_PI / CN), &sf, &cf);
      float wr = (half & m & 1) ? -1.f : 1.f, wi = 0.f;
      float rr = 0.f, ri = 0.f;
      const float* rw = rowl + w * 64 + half * 32;
      #pragma unroll 8
      for (int j = 0; j < 32; ++j) {
        float xv = rw[j];
        rr = fmaf(xv, wr, rr);
        ri = fmaf(-xv, wi, ri);
        float nr = wr * cf - wi * sf; wi = wi * cf + wr * sf; wr = nr;
      }
      rr += __shfl_xor(rr, 32);
      ri += __shfl_xor(ri, 32);
      am = sqrtf(rr * rr + ri * ri);
      if (half == 0) { Rr[w * 32 + m] = rr; Ri[w * 32 + m] = ri; aR[w * 32 + m] = am; }
      amax = am;
      #pragma unroll
      for (int s2 = 1; s2 < 32; s2 <<= 1) amax = fmaxf(amax, __shfl_xor(amax, s2));
    }
    __syncthreads();
    // attention: single n2 loop, 4 unrolled (h,m) pairs; shared aR/Rr/Ri reads; exp2
    {
      float base2 = 0.25f * 1.44269504f * am;  // fold log2(e) into alpha
      int hb = lane >> 5;
      float al0 = chl[hb] * base2;
      float al1 = chl[hb + 2] * base2;
      float al2 = chl[hb + 4] * base2;
      float al3 = chl[hb + 6] * base2;
      float den0 = 0, sr0 = 0, si0 = 0, den1 = 0, sr1 = 0, si1 = 0;
      float den2 = 0, sr2 = 0, si2 = 0, den3 = 0, sr3 = 0, si3 = 0;
      const float* aRw = aR + w * 32;
      const float* Rrw = Rr + w * 32;
      const float* Riw = Ri + w * 32;
      for (int n2 = 0; n2 < CM; ++n2) {
        float d = aRw[n2] - amax;
        float rrn = Rrw[n2], rin = Riw[n2];
        float e0 = exp2f(al0 * d); den0 += e0; sr0 = fmaf(e0, rrn, sr0); si0 = fmaf(e0, rin, si0);
        float e1 = exp2f(al1 * d); den1 += e1; sr1 = fmaf(e1, rrn, sr1); si1 = fmaf(e1, rin, si1);
        float e2 = exp2f(al2 * d); den2 += e2; sr2 = fmaf(e2, rrn, sr2); si2 = fmaf(e2, rin, si2);
        float e3 = exp2f(al3 * d); den3 += e3; sr3 = fmaf(e3, rrn, sr3); si3 = fmaf(e3, rin, si3);
      }
      float r0 = 1.f / den0, r1 = 1.f / den1, r2 = 1.f / den2, r3 = 1.f / den3;
      SL[w * 256 + lane      ] = make_float2(sr0 * r0, si0 * r0);
      SL[w * 256 + lane + 64 ] = make_float2(sr1 * r1, si1 * r1);
      SL[w * 256 + lane + 128] = make_float2(sr2 * r2, si2 * r2);
      SL[w * 256 + lane + 192] = make_float2(sr3 * r3, si3 * r3);
    }
    __syncthreads();
    // irfft over f (n = lane): float4 reads (2 f per read), paired phasors
    {
      int n2 = lane;
      const float2* Sw = SL + w * 256;
      float cd, sd;
      sincosf((float)n2 * (TWO_PI / CN), &sd, &cd);
      float c2 = cd * cd - sd * sd, s2 = 2.f * sd * cd;  // step 2*theta
      float pxA = 1.f, pyA = 0.f;                        // phasor for even f
      float acc[8];
      #pragma unroll
      for (int h = 0; h < CH; ++h) acc[h] = -Sw[h * 32].x; // compensates weight-2 on f=0
      for (int f2 = 0; f2 < 16; ++f2) {
        float pxB = pxA * cd - pyA * sd, pyB = pyA * cd + pxA * sd;
        #pragma unroll
        for (int h = 0; h < CH; ++h) {
          float4 sv = *(const float4*)(Sw + h * 32 + f2 * 2);
          acc[h] += 2.f * (sv.x * pxA - sv.y * pyA) + 2.f * (sv.z * pxB - sv.w * pyB);
        }
        float nx = pxA * c2 - pyA * s2; pyA = pyA * c2 + pxA * s2; pxA = nx;
      }
      int t = tbase + w;
      float* Pb = a.Pbuf + (((size_t)(b * CN + n2)) * CT + t) * CH;
      ((float4*)Pb)[0] = make_float4(acc[0] * (1.f / CN), acc[1] * (1.f / CN),
                                     acc[2] * (1.f / CN), acc[3] * (1.f / CN));
      ((float4*)Pb)[1] = make_float4(acc[4] * (1.f / CN), acc[5] * (1.f / CN),
                                     acc[6] * (1.f / CN), acc[7] * (1.f / CN));
    }
  } else if (blk < 1344) {
    // ---- k_ow ----
    float* ps = sm; // [2][96][2]
    int g = blk - 1280;
    int tc = tid >> 7, idx = tid & 127;
    if (idx < CP) {
      int p = idx, t0 = tc * 256;
      float s0, c0v, ss, cs;
      sincosf((float)((g * t0) & (CT - 1)) * (TWO_PI / CT), &s0, &c0v);
      sincosf((float)g * (TWO_PI / CT), &ss, &cs);
      float wr = c0v, wi = s0, ar = 0.f, ai = 0.f;
      #pragma unroll 16
      for (int t = 0; t < 256; ++t) {
        float w = LD(a.out_w, (size_t)(t0 + t) * CP + p, f32);
        ar = fmaf(w, wr, ar); ai = fmaf(w, wi, ai);
        float nr = wr * cs - wi * ss; wi = wi * cs + wr * ss; wr = nr;
      }
      ps[(tc * CP + p) * 2] = ar; ps[(tc * CP + p) * 2 + 1] = ai;
    }
    __syncthreads();
    if (tid < CP) {
      a.owr[g * CP + tid] = ps[tid * 2] + ps[(CP + tid) * 2];
      a.owi[g * CP + tid] = ps[tid * 2 + 1] + ps[(CP + tid) * 2 + 1];
    }
  } else if (blk < 1356) {
    // ---- k0b self-sufficient ----
    float* eml = sm;           // [128]
    float* evl = sm + 128;     // [2][16]
    float* ewoh = sm + 160;    // [2][128]
    int bi = blk - 1344;
    int half = tid >> 7, e = tid & 127;
    int pairIdx = bi * 2 + half;
    int which = pairIdx >> 3, h = pairIdx & 7;
    if (tid < 128) eml[tid] = LD(a.emb, tid, f32);
    __syncthreads();
    if (e < 16) {
      float acc = 0;
      #pragma unroll 8
      for (int d = 0; d < CD; ++d) acc += eml[d] * LD(a.cWv, d * CD + h * CDH + e, f32);
      evl[half * 16 + e] = acc;
    }
    __syncthreads();
    {
      float acc = 0;
      #pragma unroll
      for (int j = 0; j < CDH; ++j)
        acc += evl[half * 16 + j] * LD(a.cWo, (h * CDH + j) * CD + e, f32);
      ewoh[half * 128 + e] = acc;
    }
    __syncthreads();
    {
      const void* W = which == 0 ? a.tWq : (which == 1 ? a.tWk : a.tWv);
      float acc = 0;
      #pragma unroll 8
      for (int d = 0; d < CD; ++d) acc += ewoh[half * 128 + d] * LD(W, d * CD + e, f32);
      (which == 0 ? a.ewq : (which == 1 ? a.ewk : a.ewv))[h * CD + e] = acc;
    }
  } else {
    float* drl = sm;
    if (tid < 128) drl[tid] = LD(a.drw, tid, f32);
    __syncthreads();
    if (tid < 128) {
      float acc = 0;
      #pragma unroll 8
      for (int d = 0; d < CD; ++d) acc += LD(a.tWo, tid * CD + d, f32) * drl[d];
      a.wod[tid] = acc;
    }
  }
}

// ============ kC v4: 512 threads; phase-3 key loop fully register/readlane ========
// Phase 2: round-1 form (wave = 8g x 8h; 2 b128/iter, 2-way banks = free).
// Phase 3: each lane loads its QL row ONCE (qrow[16], 4 b128, stride-20 rows);
//          key loop fetches y via v_readlane (wave-uniform g) -> ZERO LDS instrs
//          in the 64-key loop except one float2 vdL broadcast per key.
//          vv never materialized: si = sum(uuy*ya - uux*yb).
__global__ __launch_bounds__(512, 4) void kC(MArgs a) {
  __shared__ __align__(16) float sm[8384];
  float* Pl = sm;                        // [64 u][68]
  float* QL = sm + 4352;                 // [64 g][20] (16 data + 4 pad)
  float* Cl = sm + 5632;                 // [512]
  float* Ul = sm + 6144;                 // [64]
  float2* vdL = (float2*)(sm + 6208);    // [8][64]
  float2* zL = (float2*)(sm + 7232);     // [8][64]
  float* zrow = sm + 8256;               // [64][2]
  bool f32 = detect_f32(a.x);
  int blk = blockIdx.x, tid = threadIdx.x;
  int b = blk >> 6, n = blk & 63;
  const float4* src4 = (const float4*)(a.Pbuf + ((size_t)(b * CN + n)) * CT * CH);
  for (int i = tid; i < 1024; i += 512) {
    float4 v = src4[i];
    int t = i >> 1, half = i & 1;
    int k = t >> 6, u = t & 63;
    float* dst = Pl + u * 68 + half * 32 + k;
    dst[0] = v.x; dst[8] = v.y; dst[16] = v.z; dst[24] = v.w;
  }
  for (int id = tid; id < 512 + 64; id += 512) {
    if (id < 512) {
      int h = id >> 6, aa = (id >> 3) & 7, b2 = id & 7;
      float c = 0;
      #pragma unroll
      for (int j = 0; j < CDH; ++j)
        c += a.ewq[aa * CD + h * CDH + j] * a.ewk[b2 * CD + h * CDH + j];
      Cl[id] = c;
    } else {
      int r = id - 512;
      int h = r >> 3, aa = r & 7;
      float c = 0;
      #pragma unroll
      for (int j = 0; j < CDH; ++j) c += a.ewv[aa * CD + h * CDH + j] * a.wod[h * CDH + j];
      Ul[r] = c;
    }
  }
  __syncthreads();
  // ---- phase 2: t-DFT (chunked, phasor recurrence) -> QL stride 20 ----
  {
    int g = tid >> 3, h = tid & 7;
    float cs, sn;
    sincosf((float)g * (TWO_PI / CT), &sn, &cs);
    float wr = 1.f, wi = 0.f;
    float car[8] = {0, 0, 0, 0, 0, 0, 0, 0};
    float cai[8] = {0, 0, 0, 0, 0, 0, 0, 0};
    #pragma unroll 4
    for (int u = 0; u < 64; ++u) {
      const float4* pu = (const float4*)(Pl + u * 68 + h * 8);
      float4 lo = pu[0], hi = pu[1];
      car[0] = fmaf(lo.x, wr, car[0]); cai[0] = fmaf(lo.x, wi, cai[0]);
      car[1] = fmaf(lo.y, wr, car[1]); cai[1] = fmaf(lo.y, wi, cai[1]);
      car[2] = fmaf(lo.z, wr, car[2]); cai[2] = fmaf(lo.z, wi, cai[2]);
      car[3] = fmaf(lo.w, wr, car[3]); cai[3] = fmaf(lo.w, wi, cai[3]);
      car[4] = fmaf(hi.x, wr, car[4]); cai[4] = fmaf(hi.x, wi, cai[4]);
      car[5] = fmaf(hi.y, wr, car[5]); cai[5] = fmaf(hi.y, wi, cai[5]);
      car[6] = fmaf(hi.z, wr, car[6]); cai[6] = fmaf(hi.z, wi, cai[6]);
      car[7] = fmaf(hi.w, wr, car[7]); cai[7] = fmaf(hi.w, wi, cai[7]);
      float nr = wr * cs + wi * sn; wi = wi * cs - wr * sn; wr = nr; // *= e^{-2pi i g/512}
    }
    float cs8, sn8;
    sincosf((float)(g & 7) * (TWO_PI / 8.f), &sn8, &cs8);
    float pr = 1.f, pi = 0.f, qr = 0.f, qi = 0.f;
    #pragma unroll
    for (int k = 0; k < 8; ++k) {
      qr += car[k] * pr - cai[k] * pi;
      qi += cai[k] * pr + car[k] * pi;
      float nr2 = pr * cs8 + pi * sn8; pi = pi * cs8 - pr * sn8; pr = nr2;
    }
    QL[g * 20 + h * 2] = qr;
    QL[g * 20 + h * 2 + 1] = qi;
  }
  __syncthreads();
  // ---- phase 3: attention, register-held Q rows ----
  int h = tid >> 6, m = tid & 63;
  float qrow[16];
  {
    const float4* q4 = (const float4*)(QL + m * 20);
    float4 q0 = q4[0], q1 = q4[1], q2 = q4[2], q3 = q4[3];
    qrow[0] = q0.x; qrow[1] = q0.y; qrow[2] = q0.z; qrow[3] = q0.w;
    qrow[4] = q1.x; qrow[5] = q1.y; qrow[6] = q1.z; qrow[7] = q1.w;
    qrow[8] = q2.x; qrow[9] = q2.y; qrow[10] = q2.z; qrow[11] = q2.w;
    qrow[12] = q3.x; qrow[13] = q3.y; qrow[14] = q3.z; qrow[15] = q3.w;
  }
  {
    float vr = 0, vi = 0;
    #pragma unroll
    for (int aa = 0; aa < 8; ++aa) {
      float u = Ul[h * 8 + aa];
      vr = fmaf(qrow[2 * aa], u, vr); vi = fmaf(qrow[2 * aa + 1], u, vi);
    }
    vdL[h * 64 + m] = make_float2(vr, vi);
  }
  float uux[8], uuy[8];
  #pragma unroll
  for (int bb = 0; bb < 8; ++bb) {
    float ax = 0, ay = 0;
    #pragma unroll
    for (int aa = 0; aa < 8; ++aa) {
      float cl = Cl[(h * 8 + aa) * 8 + bb];
      ax = fmaf(qrow[2 * aa], cl, ax);
      ay = fmaf(qrow[2 * aa + 1], cl, ay);
    }
    uux[bb] = ax; uuy[bb] = ay;
  }
  float mx = -1e30f, den = 0.f, zr = 0.f, zi = 0.f;
  #pragma unroll 4
  for (int g = 0; g < CG; ++g) {
    float sr = 0.f, si = 0.f;
    #pragma unroll
    for (int j = 0; j < 8; ++j) {
      float ya = rdlane(qrow[2 * j], g);
      float yb = rdlane(qrow[2 * j + 1], g);
      sr = fmaf(uux[j], ya, sr);
      sr = fmaf(uuy[j], yb, sr);
      si = fmaf(uuy[j], ya, si);
      si = fmaf(uux[j], -yb, si);
    }
    float s = 0.25f * sqrtf(sr * sr + si * si);
    if (s > mx) {
      float f = __expf(mx - s);
      den *= f; zr *= f; zi *= f; mx = s;
    }
    float e = __expf(s - mx);
    float2 vd = vdL[h * 64 + g];
    den += e; zr = fmaf(e, vd.x, zr); zi = fmaf(e, vd.y, zi);
  }
  {
    float rv = 1.f / den;
    zL[h * 64 + m] = make_float2(zr * rv, zi * rv);
  }
  __syncthreads();
  if (tid < 128) {
    int g = tid >> 1, c = tid & 1;
    float acc = 0;
    #pragma unroll
    for (int hh = 0; hh < CH; ++hh) acc += c ? zL[hh * 64 + g].y : zL[hh * 64 + g].x;
    zrow[g * 2 + c] = acc;
  }
  __syncthreads();
  if (tid < CP) {
    int p = tid;
    float acc = zrow[0] * a.owr[p] - zrow[1] * a.owi[p]; // g=0 (bin-0 imag dropped)
    #pragma unroll 8
    for (int g = 1; g < CG; ++g)
      acc += 2.f * (zrow[g * 2] * a.owr[g * CP + p] - zrow[g * 2 + 1] * a.owi[g * CP + p]);
    float xo = acc * (1.f / CT) + LD(a.drb, 0, f32) * a.owr[p] + LD(a.out_b, p, f32);
    float val = LD(a.wfuse, 0, f32) * xo
              + LD(a.wfuse, 1, f32) * a.trendo[((size_t)(b * CN + n)) * CP + p];
    size_t oidx = ((size_t)(b * CP + p)) * CN + n;
    if (f32) ((float*)a.out)[oidx] = val;
    else ((bf16*)a.out)[oidx] = __float2bfloat16(val);
  }
}

extern "C" void kernel_launch(void* const* d_in, const int* in_sizes, int n_in,
                              void* d_out, int out_size, void* d_ws, size_t ws_size,
                              hipStream_t stream) {
  float* W = (float*)d_ws;
  MArgs a;
  a.x = d_in[0];   a.emb = d_in[1];  a.dec_w = d_in[2]; a.dec_b = d_in[3];
  a.w1 = d_in[4];  a.b1 = d_in[5];   a.w2 = d_in[6];    a.b2 = d_in[7];
  a.w3 = d_in[8];  a.b3 = d_in[9];
  a.cWq = d_in[10]; a.cWk = d_in[11]; a.cWv = d_in[12]; a.cWo = d_in[13];
  a.tWq = d_in[14]; a.tWk = d_in[15]; a.tWv = d_in[16]; a.tWo = d_in[17];
  a.drw = d_in[18]; a.drb = d_in[19]; a.out_w = d_in[20]; a.out_b = d_in[21];
  a.wfuse = d_in[22];
  a.trendo = W; W += (size_t)CB * CN * CP;
  a.Pbuf = W;   W += (size_t)CB * CN * CT * CH;
  a.ewq = W;    W += CH * CD;
  a.ewk = W;    W += CH * CD;
  a.ewv = W;    W += CH * CD;
  a.wod = W;    W += CD;
  a.owr = W;    W += CG * CP;
  a.owi = W;    W += CG * CP;
  a.out = d_out;

  kS2<<<1357, 256, 0, stream>>>(a);
  kC<<<512, 512, 0, stream>>>(a);
}

// Round 5
// 181.668 us; speedup vs baseline: 1.0898x; 1.0898x over previous
//
#include <hip/hip_runtime.h>
#include <hip/hip_bf16.h>

typedef __hip_bfloat16 bf16;
typedef float v2f __attribute__((ext_vector_type(2)));

constexpr int CB = 8;     // batch
constexpr int CT = 512;   // T
constexpr int CN = 64;    // N
constexpr int CD = 128;   // D
constexpr int CP = 96;    // PRED
constexpr int CH = 8;     // HEADS
constexpr int CDH = 16;   // head dim
constexpr int CHID = 256; // HID
constexpr int CM = 32;    // CEM freq tokens
constexpr int CG = 64;    // TEM freq tokens
constexpr float TWO_PI = 6.28318530717958647692f;

__device__ __forceinline__ float LD(const void* p, size_t i, bool f) {
  return f ? ((const float*)p)[i] : __bfloat162float(((const bf16*)p)[i]);
}
template <bool F32>
__device__ __forceinline__ float LDT(const void* p, size_t i) {
  return F32 ? ((const float*)p)[i] : __bfloat162float(((const bf16*)p)[i]);
}

__device__ __forceinline__ bool detect_f32(const void* x) {
  const unsigned int* xw = (const unsigned int*)x;
  unsigned int w = xw[threadIdx.x & 63];
  unsigned int e = (w >> 7) & 0xFF;
  unsigned long long m = __ballot(e >= 0x90 || e <= 0x60);
  return __popcll(m) > 3;
}

struct MArgs {
  const void *x, *dec_w, *dec_b, *out_w, *emb, *cWq, *cWk, *cWv, *cWo;
  const void *tWq, *tWk, *tWv, *tWo, *drw, *drb, *out_b, *wfuse;
  const void *w1, *b1, *w2, *b2, *w3, *b3;
  float *trendo, *Pbuf, *ewq, *ewk, *ewv, *wod, *owr, *owi;
  void* out;
};

// ================= kS2 v3 (round-3 proven, ~55.5 us) =================
template <bool F32>
__device__ void k2_body(float* sm, const MArgs& a) {
  float* xbuf = sm;          // [512][3] padded (dead after decomp)
  float* rows = sm;          // [2][512] aliases xbuf (written after sync)
  float* h1 = sm + 1536;     // [2][256]
  float* h2 = sm + 2048;     // [2][256]
  int r0 = blockIdx.x * 2;
  int b = r0 >> 6, n0 = r0 & 63;
  int tid = threadIdx.x;
  size_t xb = (size_t)b * CT * CN + n0;
  for (int i = tid; i < CT * 2; i += 256) {
    int t = i >> 1, q = i & 1;
    xbuf[t * 3 + q] = LDT<F32>(a.x, xb + (size_t)t * CN + q);
  }
  __syncthreads();
  float trv[4];
  int q = tid & 1, tl = tid >> 1, t0 = tl * 4;
  {
    float w0 = LDT<F32>(a.dec_w, 0), w1 = LDT<F32>(a.dec_w, 1);
    float c0 = LDT<F32>(a.dec_b, 0), c1 = LDT<F32>(a.dec_b, 1);
    float s17 = 0.f, s49 = 0.f;
    #pragma unroll
    for (int o = -8; o <= 8; ++o) {
      int u = t0 + o; u = u < 0 ? 0 : (u > CT - 1 ? CT - 1 : u);
      s17 += xbuf[u * 3 + q];
    }
    #pragma unroll
    for (int o = -24; o <= 24; ++o) {
      int u = t0 + o; u = u < 0 ? 0 : (u > CT - 1 ? CT - 1 : u);
      s49 += xbuf[u * 3 + q];
    }
    #pragma unroll
    for (int k = 0; k < 4; ++k) {
      int t = t0 + k;
      if (k > 0) {
        int up8 = t + 8 > CT - 1 ? CT - 1 : t + 8;
        int dn9 = t - 9 < 0 ? 0 : t - 9;
        int up24 = t + 24 > CT - 1 ? CT - 1 : t + 24;
        int dn25 = t - 25 < 0 ? 0 : t - 25;
        s17 += xbuf[up8 * 3 + q] - xbuf[dn9 * 3 + q];
        s49 += xbuf[up24 * 3 + q] - xbuf[dn25 * 3 + q];
      }
      float m0 = s17 * (1.f / 17.f), m1 = s49 * (1.f / 49.f);
      float xv = xbuf[t * 3 + q];
      float l0 = xv * w0 + c0, l1 = xv * w1 + c1;
      float mx = fmaxf(l0, l1);
      float e0 = __expf(l0 - mx), e1 = __expf(l1 - mx);
      trv[k] = (e0 * m0 + e1 * m1) / (e0 + e1);
    }
  }
  __syncthreads();  // all xbuf reads done before aliasing writes
  #pragma unroll
  for (int k = 0; k < 4; ++k) rows[q * CT + t0 + k] = trv[k];
  __syncthreads();
  int c = tid;
  float a0, a1;
  {
    float bias = LDT<F32>(a.b1, c);
    a0 = a1 = 0.f;
    #pragma unroll 16
    for (int t = 0; t < CT; ++t) {
      float w = LDT<F32>(a.w1, t * CHID + c);
      a0 = fmaf(rows[t], w, a0);
      a1 = fmaf(rows[CT + t], w, a1);
    }
    h1[c] = fmaxf(a0 + bias, 0.f);
    h1[CHID + c] = fmaxf(a1 + bias, 0.f);
  }
  __syncthreads();
  {
    float bias = LDT<F32>(a.b2, c);
    a0 = a1 = 0.f;
    #pragma unroll 16
    for (int i = 0; i < CHID; ++i) {
      float w = LDT<F32>(a.w2, i * CHID + c);
      a0 = fmaf(h1[i], w, a0);
      a1 = fmaf(h1[CHID + i], w, a1);
    }
    h2[c] = fmaxf(a0 + bias, 0.f);
    h2[CHID + c] = fmaxf(a1 + bias, 0.f);
  }
  __syncthreads();
  if (tid < 2 * CP) {
    int p = tid < CP ? tid : tid - CP;
    int qh = tid < CP ? 0 : 1;
    float bias = LDT<F32>(a.b3, p);
    a0 = 0.f;
    #pragma unroll 16
    for (int i = 0; i < CHID; ++i)
      a0 = fmaf(h2[qh * CHID + i], LDT<F32>(a.w3, i * CP + p), a0);
    a.trendo[((size_t)(b * CN + n0 + qh)) * CP + p] = a0 + bias;
  }
}

__global__ __launch_bounds__(256, 4) void kS2(MArgs a) {
  __shared__ __align__(16) float sm[4608];
  bool f32 = detect_f32(a.x);
  int blk = blockIdx.x, tid = threadIdx.x;
  if (blk < 256) {
    if (f32) k2_body<true>(sm, a);
    else     k2_body<false>(sm, a);
  } else if (blk < 1280) {
    // ---- k3: inline res + CEM collapsed attention, 4 t per block (1/wave) ----
    float* xl = sm;                    // [52][64] = 3328 (dead after residual)
    float2* SL = (float2*)sm;          // [4][256] float2, aliases xl (written late)
    float* chp = sm + 3328;            // [512] early scratch
    float* rowl = sm + 3328;           // [4][64] aliases chp (written after chp dead)
    float* Rr = sm + 3584;             // [4][32]
    float* Ri = sm + 3712;
    float* aR = sm + 3840;
    float* prod = sm + 3968;           // [128]
    float* chl = sm + 4096;            // [8]
    float* eml = sm + 4104;            // [128]
    int bk = blk - 256;
    int b = bk >> 7, tbase = (bk & 127) * 4;
    int w = tid >> 6, lane = tid & 63;
    size_t xb = (size_t)b * CT * CN;
    for (int i = tid; i < 52 * 64; i += 256) {
      int r = i >> 6, n = i & 63;
      int u = tbase - 24 + r; u = u < 0 ? 0 : (u > CT - 1 ? CT - 1 : u);
      xl[i] = LD(a.x, xb + (size_t)u * CN + n, f32);
    }
    if (tid < 128) eml[tid] = LD(a.emb, tid, f32);
    __syncthreads();
    // ch: row-coalesced partial dots; wave w -> (matrix = w>>1, d-half = w&1)
    {
      const void* Wm = (w < 2) ? a.cWq : a.cWk;
      int d0 = (w & 1) * 64;
      float p0 = 0.f, p1 = 0.f;
      #pragma unroll 16
      for (int d = d0; d < d0 + 64; ++d) {
        float em = eml[d];
        p0 = fmaf(em, LD(Wm, (size_t)d * CD + lane, f32), p0);
        p1 = fmaf(em, LD(Wm, (size_t)d * CD + 64 + lane, f32), p1);
      }
      chp[w * 128 + lane] = p0;
      chp[w * 128 + 64 + lane] = p1;
    }
    __syncthreads();
    if (tid < 128) {
      float pq = chp[tid] + chp[128 + tid];
      float pk = chp[256 + tid] + chp[384 + tid];
      prod[tid] = pq * pk;
    }
    __syncthreads();
    if (tid < CH) {
      float s = 0;
      #pragma unroll
      for (int j = 0; j < 16; ++j) s += prod[tid * 16 + j];
      chl[tid] = fabsf(s);
    }
    // inline residual: s17 as subset of s49 (49 reads, partial accumulators)
    {
      int Lt = 24 + w;
      float w0 = LD(a.dec_w, 0, f32), w1 = LD(a.dec_w, 1, f32);
      float c0 = LD(a.dec_b, 0, f32), c1 = LD(a.dec_b, 1, f32);
      const float* xc = xl + Lt * 64 + lane;
      float pa = 0.f, pb = 0.f;
      #pragma unroll
      for (int o = -8; o <= 8; o += 2) pa += xc[o * 64];
      #pragma unroll
      for (int o = -7; o <= 7; o += 2) pb += xc[o * 64];
      float s17 = pa + pb;
      float qa = 0.f, qb = 0.f;
      #pragma unroll
      for (int o = 9; o <= 23; o += 2) qa += xc[o * 64] + xc[-o * 64];
      #pragma unroll
      for (int o = 10; o <= 24; o += 2) qb += xc[o * 64] + xc[-o * 64];
      float s49 = s17 + qa + qb;
      float m0 = s17 * (1.f / 17.f), m1 = s49 * (1.f / 49.f);
      float xv = xc[0];
      float l0 = xv * w0 + c0, l1 = xv * w1 + c1;
      float mx = fmaxf(l0, l1);
      float e0 = __expf(l0 - mx), e1 = __expf(l1 - mx);
      float tr = (e0 * m0 + e1 * m1) / (e0 + e1);
      rowl[w * 64 + lane] = xv - tr;
    }
    __syncthreads();
    // R-DFT over n, full wave: lane = (m, half); half sums 32 n-terms.
    float am, amax;
    {
      int m = lane & 31, half = lane >> 5;
      float cf, sf;
      sincosf((float)m * (TWO_PI / CN), &sf, &cf);
      float wr = (half & m & 1) ? -1.f : 1.f, wi = 0.f;
      float rr = 0.f, ri = 0.f;
      const float* rw = rowl + w * 64 + half * 32;
      #pragma unroll 8
      for (int j = 0; j < 32; ++j) {
        float xv = rw[j];
        rr = fmaf(xv, wr, rr);
        ri = fmaf(-xv, wi, ri);
        float nr = wr * cf - wi * sf; wi = wi * cf + wr * sf; wr = nr;
      }
      rr += __shfl_xor(rr, 32);
      ri += __shfl_xor(ri, 32);
      am = sqrtf(rr * rr + ri * ri);
      if (half == 0) { Rr[w * 32 + m] = rr; Ri[w * 32 + m] = ri; aR[w * 32 + m] = am; }
      amax = am;
      #pragma unroll
      for (int s2 = 1; s2 < 32; s2 <<= 1) amax = fmaxf(amax, __shfl_xor(amax, s2));
    }
    __syncthreads();
    // attention: single n2 loop, 4 unrolled (h,m) pairs; shared aR/Rr/Ri reads; exp2
    {
      float base2 = 0.25f * 1.44269504f * am;  // fold log2(e) into alpha
      int hb = lane >> 5;
      float al0 = chl[hb] * base2;
      float al1 = chl[hb + 2] * base2;
      float al2 = chl[hb + 4] * base2;
      float al3 = chl[hb + 6] * base2;
      float den0 = 0, sr0 = 0, si0 = 0, den1 = 0, sr1 = 0, si1 = 0;
      float den2 = 0, sr2 = 0, si2 = 0, den3 = 0, sr3 = 0, si3 = 0;
      const float* aRw = aR + w * 32;
      const float* Rrw = Rr + w * 32;
      const float* Riw = Ri + w * 32;
      for (int n2 = 0; n2 < CM; ++n2) {
        float d = aRw[n2] - amax;
        float rrn = Rrw[n2], rin = Riw[n2];
        float e0 = exp2f(al0 * d); den0 += e0; sr0 = fmaf(e0, rrn, sr0); si0 = fmaf(e0, rin, si0);
        float e1 = exp2f(al1 * d); den1 += e1; sr1 = fmaf(e1, rrn, sr1); si1 = fmaf(e1, rin, si1);
        float e2 = exp2f(al2 * d); den2 += e2; sr2 = fmaf(e2, rrn, sr2); si2 = fmaf(e2, rin, si2);
        float e3 = exp2f(al3 * d); den3 += e3; sr3 = fmaf(e3, rrn, sr3); si3 = fmaf(e3, rin, si3);
      }
      float r0 = 1.f / den0, r1 = 1.f / den1, r2 = 1.f / den2, r3 = 1.f / den3;
      SL[w * 256 + lane      ] = make_float2(sr0 * r0, si0 * r0);
      SL[w * 256 + lane + 64 ] = make_float2(sr1 * r1, si1 * r1);
      SL[w * 256 + lane + 128] = make_float2(sr2 * r2, si2 * r2);
      SL[w * 256 + lane + 192] = make_float2(sr3 * r3, si3 * r3);
    }
    __syncthreads();
    // irfft over f (n = lane): float4 reads (2 f per read), paired phasors
    {
      int n2 = lane;
      const float2* Sw = SL + w * 256;
      float cd, sd;
      sincosf((float)n2 * (TWO_PI / CN), &sd, &cd);
      float c2 = cd * cd - sd * sd, s2 = 2.f * sd * cd;  // step 2*theta
      float pxA = 1.f, pyA = 0.f;                        // phasor for even f
      float acc[8];
      #pragma unroll
      for (int h = 0; h < CH; ++h) acc[h] = -Sw[h * 32].x; // compensates weight-2 on f=0
      for (int f2 = 0; f2 < 16; ++f2) {
        float pxB = pxA * cd - pyA * sd, pyB = pyA * cd + pxA * sd;
        #pragma unroll
        for (int h = 0; h < CH; ++h) {
          float4 sv = *(const float4*)(Sw + h * 32 + f2 * 2);
          acc[h] += 2.f * (sv.x * pxA - sv.y * pyA) + 2.f * (sv.z * pxB - sv.w * pyB);
        }
        float nx = pxA * c2 - pyA * s2; pyA = pyA * c2 + pxA * s2; pxA = nx;
      }
      int t = tbase + w;
      float* Pb = a.Pbuf + (((size_t)(b * CN + n2)) * CT + t) * CH;
      ((float4*)Pb)[0] = make_float4(acc[0] * (1.f / CN), acc[1] * (1.f / CN),
                                     acc[2] * (1.f / CN), acc[3] * (1.f / CN));
      ((float4*)Pb)[1] = make_float4(acc[4] * (1.f / CN), acc[5] * (1.f / CN),
                                     acc[6] * (1.f / CN), acc[7] * (1.f / CN));
    }
  } else if (blk < 1344) {
    // ---- k_ow ----
    float* ps = sm; // [2][96][2]
    int g = blk - 1280;
    int tc = tid >> 7, idx = tid & 127;
    if (idx < CP) {
      int p = idx, t0 = tc * 256;
      float s0, c0v, ss, cs;
      sincosf((float)((g * t0) & (CT - 1)) * (TWO_PI / CT), &s0, &c0v);
      sincosf((float)g * (TWO_PI / CT), &ss, &cs);
      float wr = c0v, wi = s0, ar = 0.f, ai = 0.f;
      #pragma unroll 16
      for (int t = 0; t < 256; ++t) {
        float w = LD(a.out_w, (size_t)(t0 + t) * CP + p, f32);
        ar = fmaf(w, wr, ar); ai = fmaf(w, wi, ai);
        float nr = wr * cs - wi * ss; wi = wi * cs + wr * ss; wr = nr;
      }
      ps[(tc * CP + p) * 2] = ar; ps[(tc * CP + p) * 2 + 1] = ai;
    }
    __syncthreads();
    if (tid < CP) {
      a.owr[g * CP + tid] = ps[tid * 2] + ps[(CP + tid) * 2];
      a.owi[g * CP + tid] = ps[tid * 2 + 1] + ps[(CP + tid) * 2 + 1];
    }
  } else if (blk < 1356) {
    // ---- k0b self-sufficient ----
    float* eml = sm;           // [128]
    float* evl = sm + 128;     // [2][16]
    float* ewoh = sm + 160;    // [2][128]
    int bi = blk - 1344;
    int half = tid >> 7, e = tid & 127;
    int pairIdx = bi * 2 + half;
    int which = pairIdx >> 3, h = pairIdx & 7;
    if (tid < 128) eml[tid] = LD(a.emb, tid, f32);
    __syncthreads();
    if (e < 16) {
      float acc = 0;
      #pragma unroll 8
      for (int d = 0; d < CD; ++d) acc += eml[d] * LD(a.cWv, d * CD + h * CDH + e, f32);
      evl[half * 16 + e] = acc;
    }
    __syncthreads();
    {
      float acc = 0;
      #pragma unroll
      for (int j = 0; j < CDH; ++j)
        acc += evl[half * 16 + j] * LD(a.cWo, (h * CDH + j) * CD + e, f32);
      ewoh[half * 128 + e] = acc;
    }
    __syncthreads();
    {
      const void* W = which == 0 ? a.tWq : (which == 1 ? a.tWk : a.tWv);
      float acc = 0;
      #pragma unroll 8
      for (int d = 0; d < CD; ++d) acc += ewoh[half * 128 + d] * LD(W, d * CD + e, f32);
      (which == 0 ? a.ewq : (which == 1 ? a.ewk : a.ewv))[h * CD + e] = acc;
    }
  } else {
    float* drl = sm;
    if (tid < 128) drl[tid] = LD(a.drw, tid, f32);
    __syncthreads();
    if (tid < 128) {
      float acc = 0;
      #pragma unroll 8
      for (int d = 0; d < CD; ++d) acc += LD(a.tWo, tid * CD + d, f32) * drl[d];
      a.wod[tid] = acc;
    }
  }
}

// ============ kC v5: radix-8 decimated t-DFT (phase 2 halved) + round-1 phase 3 ========
// Q[g] = sum_u W512^{gu} * A_{g&7}[u],  A_rho[u] = sum_c P[64c+u] w8^{rho c}.
// Real input => A_{8-rho} = conj(A_rho): only classes {S0, A1, A2, A3, S4} stored.
// Stage 1: per (u,h) radix-8 butterfly (~30 ops) -> Ab[u][h][5][2] (20 KB LDS).
// Stage 2: per (g,h): 64 iters x (1 ds_read_b64 + 5 fma + 4 phasor) -- was 16 fma + 2
// b128 per iter. Phase 3: round-1 LDS-broadcast key loop (proven 53.5), QL stride 20.
__global__ __launch_bounds__(512, 4) void kC(MArgs a) {
  __shared__ __align__(16) float sm[13504];
  float* Pl = sm;                        // [64 u][68]
  float* QL = sm + 4352;                 // [64 g][20] (16 data + 4 pad)
  float* Cl = sm + 5632;                 // [512]
  float* Ul = sm + 6144;                 // [64]
  float2* vdL = (float2*)(sm + 6208);    // [8][64]
  float2* zL = (float2*)(sm + 7232);     // [8][64]
  float* zrow = sm + 8256;               // [64][2]
  float* Ab = sm + 8384;                 // [64 u][8 h][5 rc][2] = 5120
  bool f32 = detect_f32(a.x);
  int blk = blockIdx.x, tid = threadIdx.x;
  int b = blk >> 6, n = blk & 63;
  const float4* src4 = (const float4*)(a.Pbuf + ((size_t)(b * CN + n)) * CT * CH);
  for (int i = tid; i < 1024; i += 512) {
    float4 v = src4[i];
    int t = i >> 1, half = i & 1;
    int k = t >> 6, u = t & 63;
    float* dst = Pl + u * 68 + half * 32 + k;
    dst[0] = v.x; dst[8] = v.y; dst[16] = v.z; dst[24] = v.w;
  }
  for (int id = tid; id < 512 + 64; id += 512) {
    if (id < 512) {
      int h = id >> 6, aa = (id >> 3) & 7, b2 = id & 7;
      float c = 0;
      #pragma unroll
      for (int j = 0; j < CDH; ++j)
        c += a.ewq[aa * CD + h * CDH + j] * a.ewk[b2 * CD + h * CDH + j];
      Cl[id] = c;
    } else {
      int r = id - 512;
      int h = r >> 3, aa = r & 7;
      float c = 0;
      #pragma unroll
      for (int j = 0; j < CDH; ++j) c += a.ewv[aa * CD + h * CDH + j] * a.wod[h * CDH + j];
      Ul[r] = c;
    }
  }
  __syncthreads();
  // ---- stage 1: radix-8 butterfly over c per (u,h) ----
  {
    int u = tid >> 3, h = tid & 7;
    const float* pr = Pl + u * 68 + h * 8;   // same 2xb128, 2-way banks = free
    float p0 = pr[0], p1 = pr[1], p2 = pr[2], p3 = pr[3];
    float p4 = pr[4], p5 = pr[5], p6 = pr[6], p7 = pr[7];
    const float s = 0.70710678118654752f;
    float p04a = p0 + p4, p04s = p0 - p4;
    float p26a = p2 + p6, p26s = p2 - p6;
    float p17a = p1 + p7, p17s = p1 - p7;
    float p35a = p3 + p5, p35s = p3 - p5;
    float e1 = s * (p17a - p35a);
    float e2 = s * (p17s + p35s);
    float* ab = Ab + u * 80 + h * 10;
    ab[0] = p04a + p26a + p17a + p35a;        // S0 (rho=0), im=0
    ab[1] = 0.f;
    ab[2] = p04s + e1;                        // A1
    ab[3] = -e2 - p26s;
    ab[4] = p04a - p26a;                      // A2
    ab[5] = -(p17s - p35s);
    ab[6] = p04s - e1;                        // A3
    ab[7] = -e2 + p26s;
    ab[8] = (p04a + p26a) - (p17a + p35a);    // S4 (rho=4), im=0
    ab[9] = 0.f;
  }
  __syncthreads();
  // ---- stage 2: Q[g][h] = sum_u W512^{gu} A_eff[u]  (conj for rho>4) ----
  {
    int g = tid >> 3, h = tid & 7;
    int rho = g & 7;
    int rc = rho < 5 ? rho : 8 - rho;
    float csgn = rho < 5 ? 1.f : -1.f;
    float cs, sn;
    sincosf((float)g * (TWO_PI / CT), &sn, &cs);
    float wr = 1.f, wi = 0.f, qr = 0.f, qi = 0.f;
    const float2* ab = (const float2*)(Ab + h * 10 + rc * 2);
    #pragma unroll 4
    for (int u = 0; u < 64; ++u) {
      float2 A = ab[u * 40];
      float are = A.x, aim = csgn * A.y;
      qr = fmaf(are, wr, qr); qr = fmaf(-aim, wi, qr);
      qi = fmaf(are, wi, qi); qi = fmaf(aim, wr, qi);
      float nr = wr * cs + wi * sn; wi = wi * cs - wr * sn; wr = nr; // *= e^{-2pi i g/512}
    }
    QL[g * 20 + h * 2] = qr;
    QL[g * 20 + h * 2 + 1] = qi;
  }
  __syncthreads();
  // ---- phase 3: attention (round-1 form, stride-20 QL) ----
  int h = tid >> 6, m = tid & 63;
  v2f qp[8];
  {
    const float4* q4 = (const float4*)(QL + m * 20);
    #pragma unroll
    for (int j = 0; j < 4; ++j) {
      float4 qv = q4[j];
      qp[2 * j]     = (v2f){qv.x, qv.y};
      qp[2 * j + 1] = (v2f){qv.z, qv.w};
    }
  }
  {
    float vr = 0, vi = 0;
    #pragma unroll
    for (int aa = 0; aa < 8; ++aa) {
      float u = Ul[h * 8 + aa];
      vr = fmaf(qp[aa].x, u, vr); vi = fmaf(qp[aa].y, u, vi);
    }
    vdL[h * 64 + m] = make_float2(vr, vi);   // read back by same wave only
  }
  v2f uu[8], vv[8];
  #pragma unroll
  for (int bb = 0; bb < 8; ++bb) {
    v2f acc = {0.f, 0.f};
    #pragma unroll
    for (int aa = 0; aa < 8; ++aa) acc += qp[aa] * Cl[(h * 8 + aa) * 8 + bb];
    uu[bb] = acc;
    vv[bb] = (v2f){acc.y, -acc.x};
  }
  float mx = -1e30f, den = 0.f, zr = 0.f, zi = 0.f;
  #pragma unroll 4
  for (int g = 0; g < CG; ++g) {
    const float4* y4 = (const float4*)(QL + g * 20);  // wave-uniform: broadcast
    v2f sr2 = {0.f, 0.f}, si2 = {0.f, 0.f};
    #pragma unroll
    for (int j = 0; j < 4; ++j) {
      float4 yv = y4[j];
      v2f ya = {yv.x, yv.y}, yb = {yv.z, yv.w};
      sr2 = uu[2 * j] * ya + sr2;
      si2 = vv[2 * j] * ya + si2;
      sr2 = uu[2 * j + 1] * yb + sr2;
      si2 = vv[2 * j + 1] * yb + si2;
    }
    float sr = sr2.x + sr2.y;
    float si = si2.x + si2.y;
    float s = 0.25f * sqrtf(sr * sr + si * si);
    if (s > mx) {
      float f = __expf(mx - s);
      den *= f; zr *= f; zi *= f; mx = s;
    }
    float e = __expf(s - mx);
    float2 vd = vdL[h * 64 + g];
    den += e; zr = fmaf(e, vd.x, zr); zi = fmaf(e, vd.y, zi);
  }
  {
    float rv = 1.f / den;
    zL[h * 64 + m] = make_float2(zr * rv, zi * rv);
  }
  __syncthreads();
  if (tid < 128) {
    int g = tid >> 1, c = tid & 1;
    float acc = 0;
    #pragma unroll
    for (int hh = 0; hh < CH; ++hh) acc += c ? zL[hh * 64 + g].y : zL[hh * 64 + g].x;
    zrow[g * 2 + c] = acc;
  }
  __syncthreads();
  if (tid < CP) {
    int p = tid;
    float acc = zrow[0] * a.owr[p] - zrow[1] * a.owi[p]; // g=0 (bin-0 imag dropped)
    #pragma unroll 8
    for (int g = 1; g < CG; ++g)
      acc += 2.f * (zrow[g * 2] * a.owr[g * CP + p] - zrow[g * 2 + 1] * a.owi[g * CP + p]);
    float xo = acc * (1.f / CT) + LD(a.drb, 0, f32) * a.owr[p] + LD(a.out_b, p, f32);
    float val = LD(a.wfuse, 0, f32) * xo
              + LD(a.wfuse, 1, f32) * a.trendo[((size_t)(b * CN + n)) * CP + p];
    size_t oidx = ((size_t)(b * CP + p)) * CN + n;
    if (f32) ((float*)a.out)[oidx] = val;
    else ((bf16*)a.out)[oidx] = __float2bfloat16(val);
  }
}

extern "C" void kernel_launch(void* const* d_in, const int* in_sizes, int n_in,
                              void* d_out, int out_size, void* d_ws, size_t ws_size,
                              hipStream_t stream) {
  float* W = (float*)d_ws;
  MArgs a;
  a.x = d_in[0];   a.emb = d_in[1];  a.dec_w = d_in[2]; a.dec_b = d_in[3];
  a.w1 = d_in[4];  a.b1 = d_in[5];   a.w2 = d_in[6];    a.b2 = d_in[7];
  a.w3 = d_in[8];  a.b3 = d_in[9];
  a.cWq = d_in[10]; a.cWk = d_in[11]; a.cWv = d_in[12]; a.cWo = d_in[13];
  a.tWq = d_in[14]; a.tWk = d_in[15]; a.tWv = d_in[16]; a.tWo = d_in[17];
  a.drw = d_in[18]; a.drb = d_in[19]; a.out_w = d_in[20]; a.out_b = d_in[21];
  a.wfuse = d_in[22];
  a.trendo = W; W += (size_t)CB * CN * CP;
  a.Pbuf = W;   W += (size_t)CB * CN * CT * CH;
  a.ewq = W;    W += CH * CD;
  a.ewk = W;    W += CH * CD;
  a.ewv = W;    W += CH * CD;
  a.wod = W;    W += CD;
  a.owr = W;    W += CG * CP;
  a.owi = W;    W += CG * CP;
  a.out = d_out;

  kS2<<<1357, 256, 0, stream>>>(a);
  kC<<<512, 512, 0, stream>>>(a);
}